// Round 10
// baseline (87.133 us; speedup 1.0000x reference)
//
#include <hip/hip_runtime.h>
#include <stdint.h>

typedef __attribute__((ext_vector_type(8))) short bf16x8;
typedef __attribute__((ext_vector_type(4))) float f32x4;
typedef __attribute__((ext_vector_type(16))) float f32x16;
typedef unsigned short ushort_t;

#define B_ 8
#define S_ 2048
#define D_ 2048
#define E_ 8
#define J_ 128
#define AROWS 136             // 128 lora_A + 8 gw
#define ATILE (AROWS * 64)    // shorts per k64-tile = 8704 (17 KB)

static __device__ __forceinline__ unsigned short f2bf(float f) {
  union { float f; uint32_t u; } v; v.f = f;
  uint32_t u = v.u;
  return (unsigned short)((u + 0x7FFFu + ((u >> 16) & 1u)) >> 16);
}
static __device__ __forceinline__ float bf2f(ushort_t h) {
  union { uint32_t u; float f; } v; v.u = ((uint32_t)h) << 16;
  return v.f;
}
// HW packed convert: dst = {lo=bf16(a), hi=bf16(b)} (RNE)
static __device__ __forceinline__ uint32_t pkbf(float a, float b) {
  uint32_t r;
  asm("v_cvt_pk_bf16_f32 %0, %1, %2" : "=v"(r) : "v"(a), "v"(b));
  return r;
}

#define GLL16(gsrc, ldst)                                                        \
  __builtin_amdgcn_global_load_lds(                                              \
      (const __attribute__((address_space(1))) void*)(gsrc),                     \
      (__attribute__((address_space(3))) void*)(ldst), 16, 0, 0)

#define SBAR() __builtin_amdgcn_sched_barrier(0)

// counted-vmcnt barrier: drain all but newest N vmem ops; drain ds ops; barrier.
#define VMBAR(N)                                                                 \
  do {                                                                           \
    asm volatile("s_waitcnt vmcnt(" #N ") lgkmcnt(0)\n\ts_barrier" ::: "memory");\
    __builtin_amdgcn_sched_barrier(0);                                           \
  } while (0)

// K0: AgE[kt][row 0..135][c 0..7][8]: chunk-swizzled bf16 A_ext; storage chunk c
// of row holds logical chunk c^(row&7). Rows: 0-127 lora_A, 128-135 gw.
// Bg[d][j] = bf16(lora_B[e][d][r]), j = e*16+r.
__global__ void k_prep(const float* __restrict__ lA, const float* __restrict__ lB,
                       const float* __restrict__ gw,
                       ushort_t* __restrict__ AgE, ushort_t* __restrict__ Bg) {
  int gid = blockIdx.x * blockDim.x + threadIdx.x;
  int stride = gridDim.x * blockDim.x;
  for (int o = gid; o < 32 * AROWS * 8; o += stride) {   // 16B chunks
    int kt = o / (AROWS * 8);
    int rem = o - kt * (AROWS * 8);
    int row = rem >> 3, c = rem & 7;
    int d = kt * 64 + (((c ^ row) & 7) << 3);
    const float* src = (row < 128) ? (lA + (size_t)row * D_ + d)
                                   : (gw + (size_t)(row - 128) * D_ + d);
    float4 v0 = *(const float4*)src;
    float4 v1 = *(const float4*)(src + 4);
    bf16x8 outv;
    outv[0] = (short)f2bf(v0.x); outv[1] = (short)f2bf(v0.y);
    outv[2] = (short)f2bf(v0.z); outv[3] = (short)f2bf(v0.w);
    outv[4] = (short)f2bf(v1.x); outv[5] = (short)f2bf(v1.y);
    outv[6] = (short)f2bf(v1.z); outv[7] = (short)f2bf(v1.w);
    *(bf16x8*)&AgE[(size_t)o * 8] = outv;
  }
  for (int o4 = gid; o4 < (D_ * J_) / 4; o4 += stride) {
    int j4 = o4 & 31, dd = o4 >> 5;
    int e = j4 >> 2, r0 = (j4 & 3) * 4;
    float4 v = *(const float4*)(lB + ((size_t)e * D_ + dd) * 16 + r0);
    uint2 pk;
    pk.x = (uint32_t)f2bf(v.x) | ((uint32_t)f2bf(v.y) << 16);
    pk.y = (uint32_t)f2bf(v.z) | ((uint32_t)f2bf(v.w) << 16);
    ((uint2*)Bg)[o4] = pk;
  }
}

// K1: midb[b][s][j] (bf16) = x . A^T via 32x32x16 MFMA.
// Depth-2 pipelines: A triple-buffered LDS (stage t+2), x 3 register sets
// (load t+3, LDS-write t+1). One counted-vmcnt barrier per k64-tile.
__global__ __launch_bounds__(256) void k_mid(const float* __restrict__ x,
    const ushort_t* __restrict__ AgE, ushort_t* __restrict__ midb,
    float* __restrict__ lpart) {
  __shared__ ushort_t Ab[3][ATILE];   // 3 x 17 KB
  __shared__ ushort_t Xb[2][2048];    // 2 x 4 KB: 32 rows x 8 chunks, swizzled
  const int tid = threadIdx.x;
  const int w = tid >> 6, lane = tid & 63;
  const int l31 = lane & 31, hi = lane >> 5;
  const int b = blockIdx.y, s0 = blockIdx.x * 32;
  const float* xb = x + ((size_t)(b * S_ + s0)) * D_;
  const int xr = tid >> 4, xc = (tid & 15) * 4;
  const float* xsrc0 = xb + (size_t)xr * D_ + xc;
  const float* xsrc1 = xb + (size_t)(16 + xr) * D_ + xc;
  const int xw0 = xr * 64 + ((((xc >> 3) ^ (xr & 7))) << 3) + ((xc >> 2) & 1) * 4;
  const int xw1 = (16 + xr) * 64 + ((((xc >> 3) ^ ((16 + xr) & 7))) << 3) + ((xc >> 2) & 1) * 4;

  f32x16 acc = {};
  f32x16 acc2 = {};

  auto stageA = [&](int buf, int kt) {
#pragma unroll
    for (int c = 0; c < 4; ++c) {          // rows 0-127 (lora_A)
      int ch = c * 256 + tid;
      const ushort_t* src = AgE + (size_t)kt * ATILE + (size_t)ch * 8;
      GLL16(src, &Ab[buf][ch * 8]);
    }
    {                                       // rows 128-135 (gw): all waves, same
      int ch = 1024 + lane;                 // dest (idempotent) -> uniform vmcnt
      const ushort_t* src = AgE + (size_t)kt * ATILE + (size_t)ch * 8;
      GLL16(src, &Ab[buf][(1024 + (tid & 63)) * 8]);
    }
  };
  auto loadX = [&](float4* xr4, int t) {
    xr4[0] = *(const float4*)(xsrc0 + t * 64);
    xr4[1] = *(const float4*)(xsrc1 + t * 64);
  };
  auto cvtWrite = [&](int buf, const float4* xr4) {
    uint2 p0, p1;
    p0.x = pkbf(xr4[0].x, xr4[0].y); p0.y = pkbf(xr4[0].z, xr4[0].w);
    p1.x = pkbf(xr4[1].x, xr4[1].y); p1.y = pkbf(xr4[1].z, xr4[1].w);
    *(uint2*)&Xb[buf][xw0] = p0;
    *(uint2*)&Xb[buf][xw1] = p1;
  };
  auto computeTile = [&](int t, int ab) {
    const int cb = t & 1;
#pragma unroll
    for (int ks = 0; ks < 4; ++ks) {
      const int cc = ks * 2 + hi;
      bf16x8 xf = *(const bf16x8*)&Xb[cb][l31 * 64 + ((cc ^ (l31 & 7)) << 3)];
      const int arow = w * 32 + l31;
      bf16x8 af = *(const bf16x8*)&Ab[ab][arow * 64 + ((cc ^ (l31 & 7)) << 3)];
      acc = __builtin_amdgcn_mfma_f32_32x32x16_bf16(af, xf, acc, 0, 0, 0);
      if (w == 3) {
        const int arow2 = 128 + l31;   // rows >=136 read garbage; C rows 8-31 unused
        bf16x8 af2 = *(const bf16x8*)&Ab[ab][arow2 * 64 + ((cc ^ (l31 & 7)) << 3)];
        acc2 = __builtin_amdgcn_mfma_f32_32x32x16_bf16(af2, xf, acc2, 0, 0, 0);
      }
    }
  };

  float4 xR0[2], xR1[2], xR2[2];
  // prologue: x first (so cvtWrite's auto-wait doesn't drain A), then A(0),A(1)
  loadX(xR0, 0); loadX(xR1, 1); loadX(xR2, 2);
  SBAR();
  stageA(0, 0); stageA(1, 1);
  SBAR();
  cvtWrite(0, xR0);
  SBAR();

  // body(t): VMBAR(drain A(t)); stageA(t+2); cvtWrite x(t+1); loadX x(t+3); compute(t)
  // peeled t=0 (VMBAR 5) and t=1 (VMBAR 7); steady t=2..28 (VMBAR 9) in 3-unroll
  {
    VMBAR(5);
    stageA(2, 2); SBAR();
    cvtWrite(1, xR1); SBAR();
    loadX(xR0, 3); SBAR();
    computeTile(0, 0);
  }
  {
    VMBAR(7);
    stageA(0, 3); SBAR();
    cvtWrite(0, xR2); SBAR();
    loadX(xR1, 4); SBAR();
    computeTile(1, 1);
  }
#pragma unroll 1
  for (int k3 = 0; k3 < 9; ++k3) {
    const int t = 3 * k3 + 2;
    {
      VMBAR(9);
      stageA(1, t + 2); SBAR();
      cvtWrite((t + 1) & 1, xR0); SBAR();
      loadX(xR2, t + 3); SBAR();
      computeTile(t, 2);
    }
    {
      VMBAR(9);
      stageA(2, t + 3); SBAR();
      cvtWrite((t + 2) & 1, xR1); SBAR();
      loadX(xR0, t + 4); SBAR();
      computeTile(t + 1, 0);
    }
    {
      VMBAR(9);
      stageA(0, t + 4); SBAR();
      cvtWrite((t + 3) & 1, xR2); SBAR();
      loadX(xR1, t + 5); SBAR();
      computeTile(t + 2, 1);
    }
  }
  // t = 29 (29 % 3 == 2 -> sub0 pattern, no loadX)
  {
    VMBAR(9);
    stageA(1, 31); SBAR();
    cvtWrite(0, xR0); SBAR();     // x(30), (30&1)=0
    computeTile(29, 2);
  }
  // t = 30: no stage, cvtWrite x(31)
  {
    VMBAR(7);
    cvtWrite(1, xR1); SBAR();     // x(31), (31&1)=1
    computeTile(30, 0);
  }
  // t = 31
  {
    VMBAR(0);
    computeTile(31, 1);
  }

  // midb store: C layout col(s)=l31, row(j)=(q&3)+8*(q>>2)+4*hi.
  {
    ushort_t* mp = midb + ((size_t)(b * S_ + s0 + l31)) * J_ + w * 32 + 4 * hi;
#pragma unroll
    for (int G = 0; G < 4; ++G) {
      uint2 pk;
      pk.x = pkbf(acc[G * 4 + 0], acc[G * 4 + 1]);
      pk.y = pkbf(acc[G * 4 + 2], acc[G * 4 + 3]);
      *(uint2*)&mp[G * 8] = pk;
    }
  }

  // logits: wave 3's gw tile; experts = rows q + 4*hi (q<4).
  if (w == 3) {
    float lsq[4];
#pragma unroll
    for (int q = 0; q < 4; ++q) {
      float v = acc2[q];
      v += __shfl_xor(v, 1); v += __shfl_xor(v, 2);
      v += __shfl_xor(v, 4); v += __shfl_xor(v, 8);
      v += __shfl_xor(v, 16);
      lsq[q] = v;
    }
    if (l31 == 0) {
      float* lp = lpart + ((size_t)(b * 64 + blockIdx.x)) * 8 + hi * 4;
      lp[0] = lsq[0]; lp[1] = lsq[1]; lp[2] = lsq[2]; lp[3] = lsq[3];
    }
  }
}

// K1.5: deterministic router. Fixed-order sum of the 64 per-block partials,
// + biases, top-2, softmax -> rinfo[b] = {i1, i2, w1, w2}.
__global__ void k_router(const float* __restrict__ lpart,
                         const float* __restrict__ tb, const float* __restrict__ mb,
                         const int* __restrict__ task_p, const int* __restrict__ mode_p,
                         float* __restrict__ rinfo) {
  __shared__ float lg[64];
  const int t = threadIdx.x;           // 64 threads
  const int b = t >> 3, e = t & 7;
  float s = 0.f;
  for (int k = 0; k < 64; ++k) s += lpart[((size_t)(b * 64 + k)) * 8 + e];
  lg[t] = s * (1.f / (float)S_) + tb[task_p[0] * E_ + e] + mb[mode_p[0] * E_ + e];
  __syncthreads();
  if (t < B_) {
    float v[8];
#pragma unroll
    for (int e2 = 0; e2 < 8; ++e2) v[e2] = lg[t * 8 + e2];
    int i1 = 0;
#pragma unroll
    for (int e2 = 1; e2 < 8; ++e2) if (v[e2] > v[i1]) i1 = e2;
    int i2 = (i1 == 0) ? 1 : 0;
#pragma unroll
    for (int e2 = 0; e2 < 8; ++e2) if (e2 != i1 && v[e2] > v[i2]) i2 = e2;
    float ex = __expf(v[i2] - v[i1]);
    float w1 = 1.f / (1.f + ex), w2 = ex * w1;
    float4 r;
    r.x = (float)i1; r.y = (float)i2; r.z = w1; r.w = w2;
    ((float4*)rinfo)[t] = r;
  }
}

// K2: out[b][s][d] = sum over 2 active experts (K=32) of mid_bf16 * (coeff*B).
__global__ __launch_bounds__(256) void k_comb(const ushort_t* __restrict__ midb,
    const float* __restrict__ rinfo, const ushort_t* __restrict__ Bg,
    float* __restrict__ out) {
  __shared__ ushort_t Bt[128][40];   // [d-row][2 experts x 16 j], +8 pad
  const int n = blockIdx.x, m = blockIdx.y, b = blockIdx.z;
  const int tid = threadIdx.x, w = tid >> 6, lane = tid & 63;
  const int lm = lane & 15, g = lane >> 4;

  const float4 ri = ((const float4*)rinfo)[b];
  const int i1 = (int)ri.x, i2 = (int)ri.y;
  const float w1 = ri.z, w2 = ri.w;

  // stage active-expert B slice, scaled by combine weight
#pragma unroll
  for (int c = 0; c < 2; ++c) {
    int ci = c * 256 + tid;
    int d = ci >> 2, sub = ci & 3;
    int e = (sub & 2) ? i2 : i1;
    float sc = (sub & 2) ? w2 : w1;
    bf16x8 bv = *(const bf16x8*)(Bg + ((size_t)(n * 128 + d)) * J_ + e * 16 + (sub & 1) * 8);
    bf16x8 bw;
#pragma unroll
    for (int i = 0; i < 8; ++i) bw[i] = (short)f2bf(bf2f((ushort_t)bv[i]) * sc);
    *(bf16x8*)&Bt[d][sub * 8] = bw;
  }

  // P fragment: raw bf16 mid loads of the active 32 j-columns
  const int srow = m * 64 + w * 16 + lm;
  const int jw = (g < 2) ? (i1 * 16 + g * 8) : (i2 * 16 + (g - 2) * 8);
  bf16x8 pf = *(const bf16x8*)&midb[((size_t)(b * S_ + srow)) * J_ + jw];
  __syncthreads();

  f32x4 acc[8] = {};
#pragma unroll
  for (int nn = 0; nn < 8; ++nn) {
    bf16x8 af = *(const bf16x8*)&Bt[nn * 16 + lm][g * 8];
    acc[nn] = __builtin_amdgcn_mfma_f32_16x16x32_bf16(af, pf, acc[nn], 0, 0, 0);
  }

  float* op = out + ((size_t)(b * S_ + srow)) * D_ + n * 128;
#pragma unroll
  for (int nn = 0; nn < 8; ++nn)
    *(f32x4*)&op[nn * 16 + g * 4] = acc[nn];
}

extern "C" void kernel_launch(void* const* d_in, const int* in_sizes, int n_in,
                              void* d_out, int out_size, void* d_ws, size_t ws_size,
                              hipStream_t stream) {
  const float* x    = (const float*)d_in[0];
  const float* gw   = (const float*)d_in[1];
  const float* tb   = (const float*)d_in[2];
  const float* mb   = (const float*)d_in[3];
  const float* lA   = (const float*)d_in[4];
  const float* lB   = (const float*)d_in[5];
  const int* task_p = (const int*)d_in[6];
  const int* mode_p = (const int*)d_in[7];
  float* out = (float*)d_out;
  char* ws = (char*)d_ws;
  ushort_t* midb = (ushort_t*)ws;                  // 4,194,304 B
  ushort_t* AgE  = (ushort_t*)(ws + 4194304);      //   557,056 B
  ushort_t* Bg   = (ushort_t*)(ws + 4751360);      //   524,288 B
  float* lpart   = (float*)(ws + 5275648);         //    16,384 B
  float* rinfo   = (float*)(ws + 5292032);         //       128 B

  hipLaunchKernelGGL(k_prep, dim3(256), dim3(256), 0, stream, lA, lB, gw, AgE, Bg);
  hipLaunchKernelGGL(k_mid, dim3(64, 8), dim3(256), 0, stream, x, AgE, midb, lpart);
  hipLaunchKernelGGL(k_router, dim3(1), dim3(64), 0, stream,
                     lpart, tb, mb, task_p, mode_p, rinfo);
  hipLaunchKernelGGL(k_comb, dim3(16, 32, 8), dim3(256), 0, stream, midb, rinfo, Bg, out);
}

// Round 11
// 80.188 us; speedup vs baseline: 1.0866x; 1.0866x over previous
//
#include <hip/hip_runtime.h>
#include <stdint.h>

typedef __attribute__((ext_vector_type(8))) short bf16x8;
typedef __attribute__((ext_vector_type(4))) float f32x4;
typedef __attribute__((ext_vector_type(16))) float f32x16;
typedef unsigned short ushort_t;

#define B_ 8
#define S_ 2048
#define D_ 2048
#define E_ 8
#define J_ 128
#define M_ 64                 // s-rows per k_mid block
#define AROWS 136             // 128 lora_A + 8 gw
#define ATILE (AROWS * 64)    // shorts per k64-tile = 8704 (17 KB); 1088 16B-chunks

static __device__ __forceinline__ unsigned short f2bf(float f) {
  union { float f; uint32_t u; } v; v.f = f;
  uint32_t u = v.u;
  return (unsigned short)((u + 0x7FFFu + ((u >> 16) & 1u)) >> 16);
}
static __device__ __forceinline__ float bf2f(ushort_t h) {
  union { uint32_t u; float f; } v; v.u = ((uint32_t)h) << 16;
  return v.f;
}
// HW packed convert: dst = {lo=bf16(a), hi=bf16(b)} (RNE)
static __device__ __forceinline__ uint32_t pkbf(float a, float b) {
  uint32_t r;
  asm("v_cvt_pk_bf16_f32 %0, %1, %2" : "=v"(r) : "v"(a), "v"(b));
  return r;
}

#define GLL16(gsrc, ldst)                                                        \
  __builtin_amdgcn_global_load_lds(                                              \
      (const __attribute__((address_space(1))) void*)(gsrc),                     \
      (__attribute__((address_space(3))) void*)(ldst), 16, 0, 0)

#define SBAR() __builtin_amdgcn_sched_barrier(0)
#define VMWAIT(N)                                                                \
  do {                                                                           \
    asm volatile("s_waitcnt vmcnt(" #N ")" ::: "memory");                        \
    __builtin_amdgcn_sched_barrier(0);                                           \
  } while (0)
#define VMBAR(N)                                                                 \
  do {                                                                           \
    asm volatile("s_waitcnt vmcnt(" #N ") lgkmcnt(0)\n\ts_barrier" ::: "memory");\
    __builtin_amdgcn_sched_barrier(0);                                           \
  } while (0)

// K0: AgE[kt][row 0..135][c 0..7][8]: chunk-swizzled bf16 A_ext; storage chunk c
// of row holds logical chunk c^(row&7). Rows: 0-127 lora_A, 128-135 gw.
// Bg[d][j] = bf16(lora_B[e][d][r]), j = e*16+r.
__global__ void k_prep(const float* __restrict__ lA, const float* __restrict__ lB,
                       const float* __restrict__ gw,
                       ushort_t* __restrict__ AgE, ushort_t* __restrict__ Bg) {
  int gid = blockIdx.x * blockDim.x + threadIdx.x;
  int stride = gridDim.x * blockDim.x;
  for (int o = gid; o < 32 * AROWS * 8; o += stride) {   // 16B chunks
    int kt = o / (AROWS * 8);
    int rem = o - kt * (AROWS * 8);
    int row = rem >> 3, c = rem & 7;
    int d = kt * 64 + (((c ^ row) & 7) << 3);
    const float* src = (row < 128) ? (lA + (size_t)row * D_ + d)
                                   : (gw + (size_t)(row - 128) * D_ + d);
    float4 v0 = *(const float4*)src;
    float4 v1 = *(const float4*)(src + 4);
    bf16x8 outv;
    outv[0] = (short)f2bf(v0.x); outv[1] = (short)f2bf(v0.y);
    outv[2] = (short)f2bf(v0.z); outv[3] = (short)f2bf(v0.w);
    outv[4] = (short)f2bf(v1.x); outv[5] = (short)f2bf(v1.y);
    outv[6] = (short)f2bf(v1.z); outv[7] = (short)f2bf(v1.w);
    *(bf16x8*)&AgE[(size_t)o * 8] = outv;
  }
  for (int o4 = gid; o4 < (D_ * J_) / 4; o4 += stride) {
    int j4 = o4 & 31, dd = o4 >> 5;
    int e = j4 >> 2, r0 = (j4 & 3) * 4;
    float4 v = *(const float4*)(lB + ((size_t)e * D_ + dd) * 16 + r0);
    uint2 pk;
    pk.x = (uint32_t)f2bf(v.x) | ((uint32_t)f2bf(v.y) << 16);
    pk.y = (uint32_t)f2bf(v.z) | ((uint32_t)f2bf(v.w) << 16);
    ((uint2*)Bg)[o4] = pk;
  }
}

// K1: midb[b][s][j] (bf16) = x . A^T via 32x32x16 MFMA.
// M=64 rows/block (grid 256 = 1/CU). Wave w: j-pair jp=w&1 (2 j-tiles),
// s-tile sp=w>>1. Per iter/wave: 1 shared xf + 2 af reads per ks (1.5 reads/MFMA).
// A triple-buffered via gload_lds; x fp32->reg->cvt_pk->swizzled LDS, depth 2.
// Exact vmcnt ledger: steady VMBAR(9) {x(t+2):4, A(t+2):5}; mid-iter vmcnt(14).
// Waves 0,2 also compute the gw tile (A rows 128-135) -> logits, deterministic.
__global__ __launch_bounds__(256) void k_mid(const float* __restrict__ x,
    const ushort_t* __restrict__ AgE, ushort_t* __restrict__ midb,
    float* __restrict__ lpart) {
  __shared__ ushort_t Ab[3][ATILE];     // 3 x 17 KB
  __shared__ ushort_t Xb[2][M_ * 64];   // 2 x 8 KB, chunk-swizzled
  const int tid = threadIdx.x;
  const int w = tid >> 6, lane = tid & 63;
  const int l31 = lane & 31, hi = lane >> 5;
  const int jp = w & 1, sp = w >> 1;
  const int b = blockIdx.y, s0 = blockIdx.x * M_;
  // x load mapping: thread -> row tid>>2, 16 floats at col (tid&3)*16
  const int xr = tid >> 2, xc4 = (tid & 3) * 16;
  const float* xsrc = x + ((size_t)(b * S_ + s0 + xr)) * D_ + xc4;
  const int lc0 = 2 * (tid & 3);        // logical chunk pair for this thread

  f32x16 accA = {}, accB = {}, acc2 = {};

  auto stageA = [&](int buf, int kt) {
#pragma unroll
    for (int c = 0; c < 4; ++c) {       // rows 0-127
      int ch = c * 256 + tid;
      GLL16(AgE + (size_t)kt * ATILE + (size_t)ch * 8, &Ab[buf][ch * 8]);
    }
    {                                    // rows 128-135 (gw): 64 chunks, all waves
      int ch = 1024 + lane;              // same dest per wave (idempotent)
      GLL16(AgE + (size_t)kt * ATILE + (size_t)ch * 8, &Ab[buf][(1024 + lane) * 8]);
    }
  };
  auto loadX = [&](float4* r4, int t) {
    const float* p = xsrc + t * 64;
    r4[0] = *(const float4*)(p);
    r4[1] = *(const float4*)(p + 4);
    r4[2] = *(const float4*)(p + 8);
    r4[3] = *(const float4*)(p + 12);
  };
  auto cvtWrite = [&](int buf, const float4* r4) {
    uint4 q0, q1;
    q0.x = pkbf(r4[0].x, r4[0].y); q0.y = pkbf(r4[0].z, r4[0].w);
    q0.z = pkbf(r4[1].x, r4[1].y); q0.w = pkbf(r4[1].z, r4[1].w);
    q1.x = pkbf(r4[2].x, r4[2].y); q1.y = pkbf(r4[2].z, r4[2].w);
    q1.z = pkbf(r4[3].x, r4[3].y); q1.w = pkbf(r4[3].z, r4[3].w);
    const int ph0 = lc0 ^ (xr & 7), ph1 = (lc0 + 1) ^ (xr & 7);
    *(uint4*)&Xb[buf][xr * 64 + ph0 * 8] = q0;
    *(uint4*)&Xb[buf][xr * 64 + ph1 * 8] = q1;
  };
  auto computeTile = [&](int t, int ab) {
    const int xbuf = t & 1;
    const int xrow = sp * 32 + l31;
    const int a0 = jp * 64 + l31, a1 = jp * 64 + 32 + l31, a2 = 128 + l31;
    const int rsw = (l31 & 7);
#pragma unroll
    for (int ks = 0; ks < 4; ++ks) {
      const int cc = ks * 2 + hi;
      const int chs = ((cc ^ rsw) << 3);
      bf16x8 xf = *(const bf16x8*)&Xb[xbuf][xrow * 64 + chs];
      bf16x8 af0 = *(const bf16x8*)&Ab[ab][a0 * 64 + chs];
      bf16x8 af1 = *(const bf16x8*)&Ab[ab][a1 * 64 + chs];
      accA = __builtin_amdgcn_mfma_f32_32x32x16_bf16(af0, xf, accA, 0, 0, 0);
      accB = __builtin_amdgcn_mfma_f32_32x32x16_bf16(af1, xf, accB, 0, 0, 0);
      if ((w & 1) == 0) {   // waves 0,2: gw tile for their s-half
        bf16x8 af2 = *(const bf16x8*)&Ab[ab][a2 * 64 + chs];
        acc2 = __builtin_amdgcn_mfma_f32_32x32x16_bf16(af2, xf, acc2, 0, 0, 0);
      }
    }
  };

  float4 xS0[4], xS1[4];
  // prologue (issue order defines the vmcnt ledger): x(0):4, A(0):5, x(1):4, A(1):5
  loadX(xS0, 0); SBAR();
  stageA(0, 0);  SBAR();
  loadX(xS1, 1); SBAR();
  stageA(1, 1);  SBAR();
  VMWAIT(14);                 // drain x(0): newer = A(0):5 + x(1):4 + A(1):5
  cvtWrite(0, xS0);
  VMBAR(9);                   // drain A(0); keep {x(1):4, A(1):5}

  // body(t): issue x(t+2); stageA(t+2); compute(t); vmcnt(14) [drain x(t+1)];
  //          cvtWrite(t+1); VMBAR(9) [drain A(t+1), keep x(t+2)+A(t+2)]
#define BODY(T, AB, ABN, XCUR, XNXT)                                             \
  do {                                                                           \
    loadX(XNXT, (T) + 2); SBAR();                                                \
    stageA((ABN), (T) + 2); SBAR();                                              \
    computeTile((T), (AB));                                                      \
    VMWAIT(14);                                                                  \
    cvtWrite(((T) + 1) & 1, XCUR);                                               \
    VMBAR(9);                                                                    \
  } while (0)

#pragma unroll 1
  for (int k6 = 0; k6 < 5; ++k6) {
    const int t0 = 6 * k6;
    BODY(t0 + 0, 0, 2, xS1, xS0);
    BODY(t0 + 1, 1, 0, xS0, xS1);
    BODY(t0 + 2, 2, 1, xS1, xS0);
    BODY(t0 + 3, 0, 2, xS0, xS1);
    BODY(t0 + 4, 1, 0, xS1, xS0);
    BODY(t0 + 5, 2, 1, xS0, xS1);
  }
#undef BODY
  // tail: t=30 (no new issues), t=31
  computeTile(30, 0);         // 30 % 3 == 0
  VMWAIT(5);                  // drain x(31): newer = A(31):5
  cvtWrite(1, xS1);           // x(31) (odd) lives in xS1
  VMBAR(0);
  computeTile(31, 1);         // 31 % 3 == 1

  // midb store: C col(s)=l31, j-row = (q&3)+8*(q>>2)+4*hi within each 32-tile
  {
    const int srow = s0 + sp * 32 + l31;
    ushort_t* mp = midb + ((size_t)(b * S_ + srow)) * J_ + jp * 64 + 4 * hi;
#pragma unroll
    for (int G = 0; G < 4; ++G) {
      uint2 pA, pB;
      pA.x = pkbf(accA[G * 4 + 0], accA[G * 4 + 1]);
      pA.y = pkbf(accA[G * 4 + 2], accA[G * 4 + 3]);
      pB.x = pkbf(accB[G * 4 + 0], accB[G * 4 + 1]);
      pB.y = pkbf(accB[G * 4 + 2], accB[G * 4 + 3]);
      *(uint2*)&mp[G * 8] = pA;
      *(uint2*)&mp[32 + G * 8] = pB;
    }
  }

  // logits: waves 0,2 (s-halves); experts = rows q + 4*hi (q<4); reduce over l31
  if ((w & 1) == 0) {
#pragma unroll
    for (int q = 0; q < 4; ++q) {
      float v = acc2[q];
      v += __shfl_xor(v, 1); v += __shfl_xor(v, 2);
      v += __shfl_xor(v, 4); v += __shfl_xor(v, 8);
      v += __shfl_xor(v, 16);
      if (l31 == 0)
        lpart[(((size_t)(b * 32 + blockIdx.x)) * 2 + sp) * 8 + hi * 4 + q] = v;
    }
  }
}

// K1.5: deterministic router. Fixed-order sum of the 64 per-block partials,
// + biases, top-2, softmax -> rinfo[b] = {i1, i2, w1, w2}.
__global__ void k_router(const float* __restrict__ lpart,
                         const float* __restrict__ tb, const float* __restrict__ mb,
                         const int* __restrict__ task_p, const int* __restrict__ mode_p,
                         float* __restrict__ rinfo) {
  __shared__ float lg[64];
  const int t = threadIdx.x;           // 64 threads
  const int b = t >> 3, e = t & 7;
  float s = 0.f;
  for (int k = 0; k < 64; ++k) s += lpart[((size_t)(b * 64 + k)) * 8 + e];
  lg[t] = s * (1.f / (float)S_) + tb[task_p[0] * E_ + e] + mb[mode_p[0] * E_ + e];
  __syncthreads();
  if (t < B_) {
    float v[8];
#pragma unroll
    for (int e2 = 0; e2 < 8; ++e2) v[e2] = lg[t * 8 + e2];
    int i1 = 0;
#pragma unroll
    for (int e2 = 1; e2 < 8; ++e2) if (v[e2] > v[i1]) i1 = e2;
    int i2 = (i1 == 0) ? 1 : 0;
#pragma unroll
    for (int e2 = 0; e2 < 8; ++e2) if (e2 != i1 && v[e2] > v[i2]) i2 = e2;
    float ex = __expf(v[i2] - v[i1]);
    float w1 = 1.f / (1.f + ex), w2 = ex * w1;
    float4 r;
    r.x = (float)i1; r.y = (float)i2; r.z = w1; r.w = w2;
    ((float4*)rinfo)[t] = r;
  }
}

// K2: out[b][s][d] = sum over 2 active experts (K=32) of mid_bf16 * (coeff*B).
__global__ __launch_bounds__(256) void k_comb(const ushort_t* __restrict__ midb,
    const float* __restrict__ rinfo, const ushort_t* __restrict__ Bg,
    float* __restrict__ out) {
  __shared__ ushort_t Bt[128][40];   // [d-row][2 experts x 16 j], +8 pad
  const int n = blockIdx.x, m = blockIdx.y, b = blockIdx.z;
  const int tid = threadIdx.x, w = tid >> 6, lane = tid & 63;
  const int lm = lane & 15, g = lane >> 4;

  const float4 ri = ((const float4*)rinfo)[b];
  const int i1 = (int)ri.x, i2 = (int)ri.y;
  const float w1 = ri.z, w2 = ri.w;

  // stage active-expert B slice, scaled by combine weight
#pragma unroll
  for (int c = 0; c < 2; ++c) {
    int ci = c * 256 + tid;
    int d = ci >> 2, sub = ci & 3;
    int e = (sub & 2) ? i2 : i1;
    float sc = (sub & 2) ? w2 : w1;
    bf16x8 bv = *(const bf16x8*)(Bg + ((size_t)(n * 128 + d)) * J_ + e * 16 + (sub & 1) * 8);
    bf16x8 bw;
#pragma unroll
    for (int i = 0; i < 8; ++i) bw[i] = (short)f2bf(bf2f((ushort_t)bv[i]) * sc);
    *(bf16x8*)&Bt[d][sub * 8] = bw;
  }

  // P fragment: raw bf16 mid loads of the active 32 j-columns
  const int srow = m * 64 + w * 16 + lm;
  const int jw = (g < 2) ? (i1 * 16 + g * 8) : (i2 * 16 + (g - 2) * 8);
  bf16x8 pf = *(const bf16x8*)&midb[((size_t)(b * S_ + srow)) * J_ + jw];
  __syncthreads();

  f32x4 acc[8] = {};
#pragma unroll
  for (int nn = 0; nn < 8; ++nn) {
    bf16x8 af = *(const bf16x8*)&Bt[nn * 16 + lm][g * 8];
    acc[nn] = __builtin_amdgcn_mfma_f32_16x16x32_bf16(af, pf, acc[nn], 0, 0, 0);
  }

  float* op = out + ((size_t)(b * S_ + srow)) * D_ + n * 128;
#pragma unroll
  for (int nn = 0; nn < 8; ++nn)
    *(f32x4*)&op[nn * 16 + g * 4] = acc[nn];
}

extern "C" void kernel_launch(void* const* d_in, const int* in_sizes, int n_in,
                              void* d_out, int out_size, void* d_ws, size_t ws_size,
                              hipStream_t stream) {
  const float* x    = (const float*)d_in[0];
  const float* gw   = (const float*)d_in[1];
  const float* tb   = (const float*)d_in[2];
  const float* mb   = (const float*)d_in[3];
  const float* lA   = (const float*)d_in[4];
  const float* lB   = (const float*)d_in[5];
  const int* task_p = (const int*)d_in[6];
  const int* mode_p = (const int*)d_in[7];
  float* out = (float*)d_out;
  char* ws = (char*)d_ws;
  ushort_t* midb = (ushort_t*)ws;                  // 4,194,304 B
  ushort_t* AgE  = (ushort_t*)(ws + 4194304);      //   557,056 B
  ushort_t* Bg   = (ushort_t*)(ws + 4751360);      //   524,288 B
  float* lpart   = (float*)(ws + 5275648);         //    16,384 B
  float* rinfo   = (float*)(ws + 5292032);         //       128 B

  hipLaunchKernelGGL(k_prep, dim3(256), dim3(256), 0, stream, lA, lB, gw, AgE, Bg);
  hipLaunchKernelGGL(k_mid, dim3(32, 8), dim3(256), 0, stream, x, AgE, midb, lpart);
  hipLaunchKernelGGL(k_router, dim3(1), dim3(64), 0, stream,
                     lpart, tb, mb, task_p, mode_p, rinfo);
  hipLaunchKernelGGL(k_comb, dim3(16, 32, 8), dim3(256), 0, stream, midb, rinfo, Bg, out);
}